// Round 1
// baseline (753.120 us; speedup 1.0000x reference)
//
#include <hip/hip_runtime.h>
#include <hip/hip_bf16.h>
#include <cstdint>

// Shapes (fixed by the problem)
#define B_    4
#define LQ    1024
#define LK    2048
#define FEAT  11
#define SP_   8
#define WD_   3
#define H_    8
#define D_    32
#define HID_  256
#define SPLITK 4
#define KSEG  (LK / SPLITK)   // 512
#define KC    16              // k-chunk for online softmax

__device__ __forceinline__ float sigmoidf_(float x) { return 1.f / (1.f + __expf(-x)); }

// ---------------------------------------------------------------------------
// Q-side projection: Qc[(b*H+h)*LQ + q][0:32] = c1 * q_struct
//                    Qc[....][32:64]          = c2 * q_wp
// ---------------------------------------------------------------------------
__global__ __launch_bounds__(256) void proj_q_kernel(
    const float* __restrict__ q_fp, const float* __restrict__ Wq_s,
    const float* __restrict__ bq_s, const float* __restrict__ Wq_w,
    const float* __restrict__ bq_w, const float* __restrict__ wb,
    float* __restrict__ Qc)
{
  const int row = blockIdx.x;            // b*LQ + q
  const int t   = threadIdx.x;           // h*32 + d
  const float alpha = sigmoidf_(wb[0]);
  const float c1 = (1.f - alpha) * 0.17677669529663687f;  // 1/sqrt(32)
  const float c2 = 2.f * alpha * 10.f;                    // 2*alpha/TEMP

  const float* x = q_fp + (size_t)row * FEAT;
  float xs[FEAT];
  #pragma unroll
  for (int f = 0; f < FEAT; ++f) xs[f] = x[f];

  float s = bq_s[t];
  #pragma unroll
  for (int f = 0; f < SP_; ++f) s += xs[f] * Wq_s[t * SP_ + f];
  float w = bq_w[t];
  #pragma unroll
  for (int f = 0; f < WD_; ++f) w += xs[SP_ + f] * Wq_w[t * WD_ + f];

  const int h = t >> 5, d = t & 31;
  const int b = row >> 10, q = row & (LQ - 1);
  float* dst = Qc + ((size_t)(b * H_ + h) * LQ + q) * 64;
  dst[d]      = c1 * s;
  dst[32 + d] = c2 * w;
}

// ---------------------------------------------------------------------------
// K-side projection: Kc[(b*H+h)*LK + k][0:32]=k_struct, [32:64]=k_wp
//                    Vp[(b*H+h)*LK + k][0:32]=values
//                    kb[(b*H+h)*LK + k] = -(alpha/TEMP)*||k_wp||^2
// ---------------------------------------------------------------------------
__global__ __launch_bounds__(256) void proj_k_kernel(
    const float* __restrict__ v_ret, const float* __restrict__ Wk_s,
    const float* __restrict__ bk_s, const float* __restrict__ Wk_w,
    const float* __restrict__ bk_w, const float* __restrict__ Wv,
    const float* __restrict__ bv,   const float* __restrict__ wb,
    float* __restrict__ Kc, float* __restrict__ Vp, float* __restrict__ kb)
{
  const int row = blockIdx.x;            // b*LK + k
  const int t   = threadIdx.x;
  const float alpha = sigmoidf_(wb[0]);

  const float* x = v_ret + (size_t)row * FEAT;
  float xs[FEAT];
  #pragma unroll
  for (int f = 0; f < FEAT; ++f) xs[f] = x[f];

  float s = bk_s[t];
  #pragma unroll
  for (int f = 0; f < SP_; ++f) s += xs[f] * Wk_s[t * SP_ + f];
  float w = bk_w[t];
  #pragma unroll
  for (int f = 0; f < WD_; ++f) w += xs[SP_ + f] * Wk_w[t * WD_ + f];
  float v = bv[t];
  #pragma unroll
  for (int f = 0; f < FEAT; ++f) v += xs[f] * Wv[t * FEAT + f];

  const int h = t >> 5, d = t & 31;
  const int b = row >> 11, k = row & (LK - 1);
  const size_t kcb = (size_t)(b * H_ + h) * LK + k;
  Kc[kcb * 64 + d]      = s;
  Kc[kcb * 64 + 32 + d] = w;
  Vp[kcb * 32 + d]      = v;

  float sq = w * w;
  #pragma unroll
  for (int off = 16; off >= 1; off >>= 1) sq += __shfl_down(sq, off, 32);
  if (d == 0) kb[kcb] = -10.f * alpha * sq;
}

// ---------------------------------------------------------------------------
// Flash attention, split-k. One block = one (split, b*h, q-tile of 256).
// Thread owns one query row. K/V/kb addresses are wave-uniform -> s_load.
// ---------------------------------------------------------------------------
__global__ __launch_bounds__(256) void attn_kernel(
    const float* __restrict__ Qc, const float* __restrict__ Kc,
    const float* __restrict__ Vp, const float* __restrict__ kb,
    const float* __restrict__ pi, float* __restrict__ part)
{
  const int s  = blockIdx.x;   // split 0..3
  const int bh = blockIdx.y;   // 0..31
  const int qt = blockIdx.z;   // 0..3
  const int tid = threadIdx.x;
  const int b = bh >> 3;
  const int q = qt * 256 + tid;

  float qreg[64];
  const float* qp = Qc + ((size_t)bh * LQ + q) * 64;
  #pragma unroll
  for (int j = 0; j < 64; ++j) qreg[j] = qp[j];

  float m = -1e30f, l = 0.f;
  float acc[32];
  #pragma unroll
  for (int d = 0; d < 32; ++d) acc[d] = 0.f;

  const int k0 = s * KSEG;
  const float* pirow = pi + ((size_t)b * LQ + q) * LK;

  for (int kc = k0; kc < k0 + KSEG; kc += KC) {
    float lg[KC], pich[KC];
    float cmax = -1e30f;
    #pragma unroll
    for (int v4 = 0; v4 < KC / 4; ++v4) {
      const float4 p4 = *reinterpret_cast<const float4*>(pirow + kc + v4 * 4);
      pich[v4 * 4 + 0] = p4.x; pich[v4 * 4 + 1] = p4.y;
      pich[v4 * 4 + 2] = p4.z; pich[v4 * 4 + 3] = p4.w;
    }
    #pragma unroll
    for (int kk = 0; kk < KC; ++kk) {
      const int k = kc + kk;
      const float* krow = Kc + ((size_t)bh * LK + k) * 64;  // uniform -> scalar
      float sdot = 0.f;
      #pragma unroll
      for (int j = 0; j < 64; ++j) sdot += qreg[j] * krow[j];
      const float lgv = sdot + kb[(size_t)bh * LK + k]
                        + __logf(fmaxf(pich[kk], 1e-9f));
      lg[kk] = lgv;
      cmax = fmaxf(cmax, lgv);
    }
    const float mnew  = fmaxf(m, cmax);
    const float scale = __expf(m - mnew);
    l *= scale;
    #pragma unroll
    for (int d = 0; d < 32; ++d) acc[d] *= scale;
    #pragma unroll
    for (int kk = 0; kk < KC; ++kk) {
      const int k = kc + kk;
      const float p = __expf(lg[kk] - mnew);
      l += p;
      const float* vrow = Vp + ((size_t)bh * LK + k) * 32;  // uniform -> scalar
      #pragma unroll
      for (int d = 0; d < 32; ++d) acc[d] += p * vrow[d];
    }
    m = mnew;
  }

  float* pp = part + ((size_t)s * (B_ * H_ * LQ) + (size_t)bh * LQ + q) * 34;
  pp[0] = m; pp[1] = l;
  #pragma unroll
  for (int d = 0; d < 32; ++d) pp[2 + d] = acc[d];
}

// ---------------------------------------------------------------------------
// Merge SPLITK partials -> ctx (B, LQ, 256) in (h*32+d) layout
// ---------------------------------------------------------------------------
__global__ __launch_bounds__(256) void combine_kernel(
    const float* __restrict__ part, float* __restrict__ ctx)
{
  const int r = blockIdx.x * 256 + threadIdx.x;  // 0..32767 = bh*LQ+q
  const int bh = r >> 10;
  const int q  = r & (LQ - 1);
  const int b = bh >> 3, h = bh & 7;

  float m = -1e30f;
  #pragma unroll
  for (int s = 0; s < SPLITK; ++s)
    m = fmaxf(m, part[((size_t)s * (B_ * H_ * LQ) + r) * 34]);

  float den = 0.f;
  float num[32];
  #pragma unroll
  for (int d = 0; d < 32; ++d) num[d] = 0.f;
  #pragma unroll
  for (int s = 0; s < SPLITK; ++s) {
    const float* pp = part + ((size_t)s * (B_ * H_ * LQ) + r) * 34;
    const float w = __expf(pp[0] - m);
    den += w * pp[1];
    #pragma unroll
    for (int d = 0; d < 32; ++d) num[d] += w * pp[2 + d];
  }
  const float inv = 1.f / den;
  float* cp = ctx + ((size_t)(b * LQ + q)) * HID_ + h * 32;
  #pragma unroll
  for (int d = 0; d < 32; ++d) cp[d] = num[d] * inv;
}

// ---------------------------------------------------------------------------
// out = ctx @ Wo^T + bo.  Block: 64 rows x 256 cols; thread: 16 rows x 4 cols.
// ---------------------------------------------------------------------------
__global__ __launch_bounds__(256) void out_kernel(
    const float* __restrict__ ctx, const float* __restrict__ Wo,
    const float* __restrict__ bo, float* __restrict__ out)
{
  __shared__ float cs[64 * 256];
  const int t = threadIdx.x;
  const size_t r0 = (size_t)blockIdx.x * 64;

  const float4* src = reinterpret_cast<const float4*>(ctx + r0 * HID_);
  float4* dst = reinterpret_cast<float4*>(cs);
  #pragma unroll
  for (int i = 0; i < 16; ++i) dst[i * 256 + t] = src[i * 256 + t];
  __syncthreads();

  const int o0 = (t & 63) * 4;
  const int rs = (t >> 6) * 16;
  float acc[16][4];
  #pragma unroll
  for (int r = 0; r < 16; ++r) {
    #pragma unroll
    for (int j = 0; j < 4; ++j) acc[r][j] = bo[o0 + j];
  }

  for (int c4 = 0; c4 < 64; ++c4) {
    const float4 w0 = *reinterpret_cast<const float4*>(Wo + (size_t)(o0 + 0) * HID_ + c4 * 4);
    const float4 w1 = *reinterpret_cast<const float4*>(Wo + (size_t)(o0 + 1) * HID_ + c4 * 4);
    const float4 w2 = *reinterpret_cast<const float4*>(Wo + (size_t)(o0 + 2) * HID_ + c4 * 4);
    const float4 w3 = *reinterpret_cast<const float4*>(Wo + (size_t)(o0 + 3) * HID_ + c4 * 4);
    #pragma unroll
    for (int r = 0; r < 16; ++r) {
      const float4 cv = *reinterpret_cast<const float4*>(cs + (rs + r) * 256 + c4 * 4);
      acc[r][0] += cv.x * w0.x + cv.y * w0.y + cv.z * w0.z + cv.w * w0.w;
      acc[r][1] += cv.x * w1.x + cv.y * w1.y + cv.z * w1.z + cv.w * w1.w;
      acc[r][2] += cv.x * w2.x + cv.y * w2.y + cv.z * w2.z + cv.w * w2.w;
      acc[r][3] += cv.x * w3.x + cv.y * w3.y + cv.z * w3.z + cv.w * w3.w;
    }
  }
  #pragma unroll
  for (int r = 0; r < 16; ++r) {
    float4 res;
    res.x = acc[r][0]; res.y = acc[r][1]; res.z = acc[r][2]; res.w = acc[r][3];
    *reinterpret_cast<float4*>(out + (r0 + rs + r) * HID_ + o0) = res;
  }
}

// ---------------------------------------------------------------------------
extern "C" void kernel_launch(void* const* d_in, const int* in_sizes, int n_in,
                              void* d_out, int out_size, void* d_ws, size_t ws_size,
                              hipStream_t stream)
{
  const float* q_fp  = (const float*)d_in[0];
  const float* v_ret = (const float*)d_in[1];
  const float* pi    = (const float*)d_in[2];
  const float* Wq_s  = (const float*)d_in[3];
  const float* bq_s  = (const float*)d_in[4];
  const float* Wk_s  = (const float*)d_in[5];
  const float* bk_s  = (const float*)d_in[6];
  const float* Wq_w  = (const float*)d_in[7];
  const float* bq_w  = (const float*)d_in[8];
  const float* Wk_w  = (const float*)d_in[9];
  const float* bk_w  = (const float*)d_in[10];
  const float* Wv    = (const float*)d_in[11];
  const float* bv    = (const float*)d_in[12];
  const float* Wo    = (const float*)d_in[13];
  const float* bo    = (const float*)d_in[14];
  const float* wb    = (const float*)d_in[15];
  float* out = (float*)d_out;

  float* ws   = (float*)d_ws;
  float* Qc   = ws;                                  // B*H*LQ*64 = 2,097,152
  float* Kc   = Qc  + (size_t)B_ * H_ * LQ * 64;     // B*H*LK*64 = 4,194,304
  float* Vp   = Kc  + (size_t)B_ * H_ * LK * 64;     // B*H*LK*32 = 2,097,152
  float* kb   = Vp  + (size_t)B_ * H_ * LK * 32;     // B*H*LK    =    65,536
  float* part = kb  + (size_t)B_ * H_ * LK;          // 4*32768*34= 4,456,448
  float* ctx  = part + (size_t)SPLITK * B_ * H_ * LQ * 34;  // 1,048,576

  proj_q_kernel<<<B_ * LQ, 256, 0, stream>>>(q_fp, Wq_s, bq_s, Wq_w, bq_w, wb, Qc);
  proj_k_kernel<<<B_ * LK, 256, 0, stream>>>(v_ret, Wk_s, bk_s, Wk_w, bk_w, Wv, bv, wb,
                                             Kc, Vp, kb);
  attn_kernel<<<dim3(SPLITK, B_ * H_, LQ / 256), 256, 0, stream>>>(Qc, Kc, Vp, kb, pi, part);
  combine_kernel<<<(B_ * H_ * LQ) / 256, 256, 0, stream>>>(part, ctx);
  out_kernel<<<(B_ * LQ) / 64, 256, 0, stream>>>(ctx, Wo, bo, out);
}

// Round 2
// 279.160 us; speedup vs baseline: 2.6978x; 2.6978x over previous
//
#include <hip/hip_runtime.h>
#include <hip/hip_bf16.h>
#include <cstdint>

#define B_    4
#define LQ    1024
#define LK    2048
#define FEAT  11
#define SP_   8
#define WD_   3
#define H_    8
#define HID_  256
#define LOG2E 1.4426950408889634f

typedef __attribute__((ext_vector_type(4))) float f32x4;
typedef __attribute__((ext_vector_type(8))) short bf16x8;
typedef __attribute__((ext_vector_type(4))) short s16x4;

__device__ __forceinline__ float sigmoidf_(float x) { return 1.f / (1.f + __expf(-x)); }

__device__ __forceinline__ short f2bf(float f) {
  unsigned u = __float_as_uint(f);
  u += 0x7fffu + ((u >> 16) & 1u);
  return (short)(u >> 16);
}
__device__ __forceinline__ float bf2f(short s) {
  return __uint_as_float(((unsigned)(unsigned short)s) << 16);
}

// ---------------------------------------------------------------------------
// Q projection -> Qh/Ql bf16 [bh][q][64], scales (c1,c2,log2e) folded in.
// ---------------------------------------------------------------------------
__global__ __launch_bounds__(256) void proj_q_kernel(
    const float* __restrict__ q_fp, const float* __restrict__ Wq_s,
    const float* __restrict__ bq_s, const float* __restrict__ Wq_w,
    const float* __restrict__ bq_w, const float* __restrict__ wb,
    short* __restrict__ Qh, short* __restrict__ Ql)
{
  const int row = blockIdx.x;            // b*LQ + q
  const int t   = threadIdx.x;           // h*32 + d
  const float alpha = sigmoidf_(wb[0]);
  const float c1 = (1.f - alpha) * 0.17677669529663687f * LOG2E;
  const float c2 = 2.f * alpha * 10.f * LOG2E;

  const float* x = q_fp + (size_t)row * FEAT;
  float xs[FEAT];
  #pragma unroll
  for (int f = 0; f < FEAT; ++f) xs[f] = x[f];

  float s = bq_s[t];
  #pragma unroll
  for (int f = 0; f < SP_; ++f) s += xs[f] * Wq_s[t * SP_ + f];
  float w = bq_w[t];
  #pragma unroll
  for (int f = 0; f < WD_; ++f) w += xs[SP_ + f] * Wq_w[t * WD_ + f];

  const int h = t >> 5, d = t & 31;
  const int b = row >> 10, q = row & (LQ - 1);
  const size_t base = ((size_t)(b * H_ + h) * LQ + q) * 64;
  const float vs = c1 * s, vw = c2 * w;
  const short hs = f2bf(vs), hw = f2bf(vw);
  Qh[base + d]      = hs;  Ql[base + d]      = f2bf(vs - bf2f(hs));
  Qh[base + 32 + d] = hw;  Ql[base + 32 + d] = f2bf(vw - bf2f(hw));
}

// ---------------------------------------------------------------------------
// K projection -> Kh bf16 [bh][k][64] (unscaled), Vp fp32 [bh][k][32],
// kb fp32 [bh][k] = -(alpha/TEMP)*log2e*||k_wp||^2
// ---------------------------------------------------------------------------
__global__ __launch_bounds__(256) void proj_k_kernel(
    const float* __restrict__ v_ret, const float* __restrict__ Wk_s,
    const float* __restrict__ bk_s, const float* __restrict__ Wk_w,
    const float* __restrict__ bk_w, const float* __restrict__ Wv,
    const float* __restrict__ bv,   const float* __restrict__ wb,
    short* __restrict__ Kh, float* __restrict__ Vp, float* __restrict__ kb)
{
  const int row = blockIdx.x;            // b*LK + k
  const int t   = threadIdx.x;
  const float alpha = sigmoidf_(wb[0]);

  const float* x = v_ret + (size_t)row * FEAT;
  float xs[FEAT];
  #pragma unroll
  for (int f = 0; f < FEAT; ++f) xs[f] = x[f];

  float s = bk_s[t];
  #pragma unroll
  for (int f = 0; f < SP_; ++f) s += xs[f] * Wk_s[t * SP_ + f];
  float w = bk_w[t];
  #pragma unroll
  for (int f = 0; f < WD_; ++f) w += xs[SP_ + f] * Wk_w[t * WD_ + f];
  float v = bv[t];
  #pragma unroll
  for (int f = 0; f < FEAT; ++f) v += xs[f] * Wv[t * FEAT + f];

  const int h = t >> 5, d = t & 31;
  const int b = row >> 11, k = row & (LK - 1);
  const size_t kcb = (size_t)(b * H_ + h) * LK + k;
  Kh[kcb * 64 + d]      = f2bf(s);
  Kh[kcb * 64 + 32 + d] = f2bf(w);
  Vp[kcb * 32 + d]      = v;

  float sq = w * w;
  #pragma unroll
  for (int off = 16; off >= 1; off >>= 1) sq += __shfl_down(sq, off, 32);
  if (d == 0) kb[kcb] = -10.f * alpha * LOG2E * sq;
}

// ---------------------------------------------------------------------------
// Transpose Vp [bh][k][32] fp32 -> Vt [bh][d][LK] bf16
// ---------------------------------------------------------------------------
__global__ __launch_bounds__(256) void vtrans_kernel(
    const float* __restrict__ Vp, short* __restrict__ Vt)
{
  __shared__ float lds[32][257];
  const int bh = blockIdx.y;
  const int k0 = blockIdx.x * 256;
  const int t  = threadIdx.x;

  const float* src = Vp + ((size_t)bh * LK + k0 + t) * 32;
  #pragma unroll
  for (int i = 0; i < 8; ++i) {
    f32x4 v = *(const f32x4*)(src + i * 4);
    lds[i * 4 + 0][t] = v[0]; lds[i * 4 + 1][t] = v[1];
    lds[i * 4 + 2][t] = v[2]; lds[i * 4 + 3][t] = v[3];
  }
  __syncthreads();

  const int d  = t >> 3;
  const int kc = (t & 7) * 32;
  short* dst = Vt + ((size_t)bh * 32 + d) * LK + k0 + kc;
  #pragma unroll
  for (int i = 0; i < 32; i += 4) {
    s16x4 hv;
    #pragma unroll
    for (int j = 0; j < 4; ++j) hv[j] = f2bf(lds[d][kc + i + j]);
    *(s16x4*)(dst + i) = hv;
  }
}

// ---------------------------------------------------------------------------
// Flash attention with MFMA. Wave = 16 q rows; chunk = 32 k.
// S^T tiles computed with permuted k-rows so C-layout == B-layout for PV.
// ---------------------------------------------------------------------------
struct Chunk {
  bf16x8 ka[2][2];   // [k-subtile][feat-half]
  bf16x8 va[2];      // [d-tile]
  f32x4  pi4[2];
  f32x4  kb4[2];
};

__device__ __forceinline__ Chunk load_chunk(
    const short* kbase, const short* vbase, const float* pibase,
    const float* kbbase, int c)
{
  Chunk ch;
  const short* kp = kbase + (size_t)c * 32 * 64;
  ch.ka[0][0] = *(const bf16x8*)(kp);
  ch.ka[0][1] = *(const bf16x8*)(kp + 32);
  ch.ka[1][0] = *(const bf16x8*)(kp + 4 * 64);
  ch.ka[1][1] = *(const bf16x8*)(kp + 4 * 64 + 32);
  const short* vp = vbase + c * 32;
  ch.va[0] = *(const bf16x8*)(vp);
  ch.va[1] = *(const bf16x8*)(vp + 16 * LK);
  const float* pp = pibase + c * 32;
  ch.pi4[0] = *(const f32x4*)(pp);
  ch.pi4[1] = *(const f32x4*)(pp + 4);
  const float* bp = kbbase + c * 32;
  ch.kb4[0] = *(const f32x4*)(bp);
  ch.kb4[1] = *(const f32x4*)(bp + 4);
  return ch;
}

__device__ __forceinline__ void attn_step(
    const Chunk& ch, bf16x8 qh0, bf16x8 qh1, bf16x8 ql0, bf16x8 ql1,
    float& m, float& l, f32x4& o0, f32x4& o1)
{
  f32x4 s0 = {0.f, 0.f, 0.f, 0.f}, s1 = {0.f, 0.f, 0.f, 0.f};
  s0 = __builtin_amdgcn_mfma_f32_16x16x32_bf16(ch.ka[0][0], qh0, s0, 0, 0, 0);
  s0 = __builtin_amdgcn_mfma_f32_16x16x32_bf16(ch.ka[0][1], qh1, s0, 0, 0, 0);
  s0 = __builtin_amdgcn_mfma_f32_16x16x32_bf16(ch.ka[0][0], ql0, s0, 0, 0, 0);
  s0 = __builtin_amdgcn_mfma_f32_16x16x32_bf16(ch.ka[0][1], ql1, s0, 0, 0, 0);
  s1 = __builtin_amdgcn_mfma_f32_16x16x32_bf16(ch.ka[1][0], qh0, s1, 0, 0, 0);
  s1 = __builtin_amdgcn_mfma_f32_16x16x32_bf16(ch.ka[1][1], qh1, s1, 0, 0, 0);
  s1 = __builtin_amdgcn_mfma_f32_16x16x32_bf16(ch.ka[1][0], ql0, s1, 0, 0, 0);
  s1 = __builtin_amdgcn_mfma_f32_16x16x32_bf16(ch.ka[1][1], ql1, s1, 0, 0, 0);

  float lg[8];
  #pragma unroll
  for (int r = 0; r < 4; ++r) {
    lg[r]     = s0[r] + ch.kb4[0][r] + __log2f(fmaxf(ch.pi4[0][r], 1e-9f));
    lg[4 + r] = s1[r] + ch.kb4[1][r] + __log2f(fmaxf(ch.pi4[1][r], 1e-9f));
  }
  float cmax = lg[0];
  #pragma unroll
  for (int j = 1; j < 8; ++j) cmax = fmaxf(cmax, lg[j]);
  cmax = fmaxf(cmax, __shfl_xor(cmax, 16));
  cmax = fmaxf(cmax, __shfl_xor(cmax, 32));
  const float mn = fmaxf(m, cmax);
  const float sc = exp2f(m - mn);

  bf16x8 pf;
  float ps = 0.f;
  #pragma unroll
  for (int j = 0; j < 8; ++j) {
    const short pb = f2bf(exp2f(lg[j] - mn));
    pf[j] = pb;
    ps += bf2f(pb);
  }
  ps += __shfl_xor(ps, 16);
  ps += __shfl_xor(ps, 32);
  l = l * sc + ps;
  m = mn;
  #pragma unroll
  for (int r = 0; r < 4; ++r) { o0[r] *= sc; o1[r] *= sc; }
  o0 = __builtin_amdgcn_mfma_f32_16x16x32_bf16(ch.va[0], pf, o0, 0, 0, 0);
  o1 = __builtin_amdgcn_mfma_f32_16x16x32_bf16(ch.va[1], pf, o1, 0, 0, 0);
}

__global__ __launch_bounds__(256, 1) void attn_kernel(
    const short* __restrict__ Qh, const short* __restrict__ Ql,
    const short* __restrict__ Kh, const short* __restrict__ Vt,
    const float* __restrict__ kb, const float* __restrict__ pi,
    float* __restrict__ ctx)
{
  const int bh = blockIdx.y;
  const int b = bh >> 3, h = bh & 7;
  const int wv = threadIdx.x >> 6;
  const int lane = threadIdx.x & 63;
  const int lo16 = lane & 15;
  const int quad = lane >> 4;
  const int q = blockIdx.x * 64 + wv * 16 + lo16;
  const int perm = ((lo16 >> 2) << 3) + (lo16 & 3);

  const size_t qoff = ((size_t)bh * LQ + q) * 64 + quad * 8;
  const bf16x8 qh0 = *(const bf16x8*)(Qh + qoff);
  const bf16x8 qh1 = *(const bf16x8*)(Qh + qoff + 32);
  const bf16x8 ql0 = *(const bf16x8*)(Ql + qoff);
  const bf16x8 ql1 = *(const bf16x8*)(Ql + qoff + 32);

  const short* kbase  = Kh + ((size_t)bh * LK + perm) * 64 + quad * 8;
  const short* vbase  = Vt + ((size_t)bh * 32 + lo16) * LK + quad * 8;
  const float* pibase = pi + ((size_t)b * LQ + q) * LK + quad * 8;
  const float* kbbase = kb + (size_t)bh * LK + quad * 8;

  float m = -1e30f, l = 0.f;
  f32x4 o0 = {0.f, 0.f, 0.f, 0.f}, o1 = {0.f, 0.f, 0.f, 0.f};

  Chunk b0 = load_chunk(kbase, vbase, pibase, kbbase, 0);
  Chunk b1 = load_chunk(kbase, vbase, pibase, kbbase, 1);
  for (int c = 0; c < 64; c += 2) {
    attn_step(b0, qh0, qh1, ql0, ql1, m, l, o0, o1);
    b0 = load_chunk(kbase, vbase, pibase, kbbase, (c + 2) & 63);
    attn_step(b1, qh0, qh1, ql0, ql1, m, l, o0, o1);
    b1 = load_chunk(kbase, vbase, pibase, kbbase, (c + 3) & 63);
  }

  const float inv = 1.0f / l;
  float* cp = ctx + ((size_t)(b * LQ + q)) * HID_ + h * 32 + quad * 4;
  f32x4 r0v, r1v;
  #pragma unroll
  for (int r = 0; r < 4; ++r) { r0v[r] = o0[r] * inv; r1v[r] = o1[r] * inv; }
  *(f32x4*)(cp)      = r0v;
  *(f32x4*)(cp + 16) = r1v;
}

// ---------------------------------------------------------------------------
// out = ctx @ Wo^T + bo.  Block: 32 rows x 256 cols; thread: 8 rows x 4 cols.
// ---------------------------------------------------------------------------
__global__ __launch_bounds__(256) void out_kernel(
    const float* __restrict__ ctx, const float* __restrict__ Wo,
    const float* __restrict__ bo, float* __restrict__ out)
{
  __shared__ float cs[32 * 256];
  const int t = threadIdx.x;
  const size_t r0 = (size_t)blockIdx.x * 32;

  const f32x4* src = reinterpret_cast<const f32x4*>(ctx + r0 * HID_);
  f32x4* dst = reinterpret_cast<f32x4*>(cs);
  #pragma unroll
  for (int i = 0; i < 8; ++i) dst[i * 256 + t] = src[i * 256 + t];
  __syncthreads();

  const int o0 = (t & 63) * 4;
  const int rs = (t >> 6) * 8;
  float acc[8][4];
  #pragma unroll
  for (int r = 0; r < 8; ++r) {
    #pragma unroll
    for (int j = 0; j < 4; ++j) acc[r][j] = bo[o0 + j];
  }

  for (int c4 = 0; c4 < 64; ++c4) {
    const f32x4 w0 = *(const f32x4*)(Wo + (size_t)(o0 + 0) * HID_ + c4 * 4);
    const f32x4 w1 = *(const f32x4*)(Wo + (size_t)(o0 + 1) * HID_ + c4 * 4);
    const f32x4 w2 = *(const f32x4*)(Wo + (size_t)(o0 + 2) * HID_ + c4 * 4);
    const f32x4 w3 = *(const f32x4*)(Wo + (size_t)(o0 + 3) * HID_ + c4 * 4);
    #pragma unroll
    for (int r = 0; r < 8; ++r) {
      const f32x4 cv = *(const f32x4*)(cs + (rs + r) * 256 + c4 * 4);
      acc[r][0] += cv[0] * w0[0] + cv[1] * w0[1] + cv[2] * w0[2] + cv[3] * w0[3];
      acc[r][1] += cv[0] * w1[0] + cv[1] * w1[1] + cv[2] * w1[2] + cv[3] * w1[3];
      acc[r][2] += cv[0] * w2[0] + cv[1] * w2[1] + cv[2] * w2[2] + cv[3] * w2[3];
      acc[r][3] += cv[0] * w3[0] + cv[1] * w3[1] + cv[2] * w3[2] + cv[3] * w3[3];
    }
  }
  #pragma unroll
  for (int r = 0; r < 8; ++r) {
    f32x4 res;
    res[0] = acc[r][0]; res[1] = acc[r][1]; res[2] = acc[r][2]; res[3] = acc[r][3];
    *(f32x4*)(out + (r0 + rs + r) * HID_ + o0) = res;
  }
}

// ---------------------------------------------------------------------------
extern "C" void kernel_launch(void* const* d_in, const int* in_sizes, int n_in,
                              void* d_out, int out_size, void* d_ws, size_t ws_size,
                              hipStream_t stream)
{
  const float* q_fp  = (const float*)d_in[0];
  const float* v_ret = (const float*)d_in[1];
  const float* pi    = (const float*)d_in[2];
  const float* Wq_s  = (const float*)d_in[3];
  const float* bq_s  = (const float*)d_in[4];
  const float* Wk_s  = (const float*)d_in[5];
  const float* bk_s  = (const float*)d_in[6];
  const float* Wq_w  = (const float*)d_in[7];
  const float* bq_w  = (const float*)d_in[8];
  const float* Wk_w  = (const float*)d_in[9];
  const float* bk_w  = (const float*)d_in[10];
  const float* Wv    = (const float*)d_in[11];
  const float* bv    = (const float*)d_in[12];
  const float* Wo    = (const float*)d_in[13];
  const float* bo    = (const float*)d_in[14];
  const float* wb    = (const float*)d_in[15];
  float* out = (float*)d_out;

  short* Qh = (short*)d_ws;                       // 32*1024*64        = 2,097,152 sh
  short* Ql = Qh + (size_t)2097152;               // 2,097,152 sh
  short* Kh = Ql + (size_t)2097152;               // 32*2048*64        = 4,194,304 sh
  short* Vt = Kh + (size_t)4194304;               // 32*32*2048        = 2,097,152 sh
  float* kbuf = (float*)(Vt + (size_t)2097152);   // 32*2048           =    65,536 fl
  float* Vp   = kbuf + (size_t)65536;             // 32*2048*32        = 2,097,152 fl
  float* ctx  = Vp + (size_t)2097152;             // 4*1024*256        = 1,048,576 fl

  proj_q_kernel<<<B_ * LQ, 256, 0, stream>>>(q_fp, Wq_s, bq_s, Wq_w, bq_w, wb, Qh, Ql);
  proj_k_kernel<<<B_ * LK, 256, 0, stream>>>(v_ret, Wk_s, bk_s, Wk_w, bk_w, Wv, bv, wb,
                                             Kh, Vp, kbuf);
  vtrans_kernel<<<dim3(LK / 256, 32), 256, 0, stream>>>(Vp, Vt);
  attn_kernel<<<dim3(LQ / 64, 32), 256, 0, stream>>>(Qh, Ql, Kh, Vt, kbuf, pi, ctx);
  out_kernel<<<(B_ * LQ) / 32, 256, 0, stream>>>(ctx, Wo, bo, out);
}